// Round 4
// baseline (140.985 us; speedup 1.0000x reference)
//
#include <hip/hip_runtime.h>

typedef unsigned short ushort_t;
typedef __attribute__((ext_vector_type(8))) short short8;   // 8 bf16 payload (4 VGPRs)
typedef __attribute__((ext_vector_type(4))) float floatx4;  // MFMA C/D + epi math
typedef __attribute__((ext_vector_type(2))) float floatx2;

#define NN    32
#define CIN   128
#define COUT  256
#define NPTS  16384            // bs*v = 4*4096
#define NSAMP (NPTS * NN)      // 524288
#define LDA   136              // LDS A-tile stride (+16B pad)
#define HB    128              // histogram partial blocks (32 per batch)

// All scratch in .so-resident device globals. NO atomics anywhere -> every
// buffer is fully overwritten each run -> no zeroing kernel, no cross-run state.
__device__ __align__(16) ushort_t g_wb[COUT * CIN];            // 64 KB: W as bf16
__device__ __align__(16) ushort_t g_y[(size_t)NPTS * COUT];    // 8 MB: Y = fsp * W^T, bf16
__device__ __align__(16) int      g_hp[HB * 4096];             // 2 MB: per-chunk histograms
__device__ __align__(16) float    g_sp[256 * 512];             // 512 KB: per-block BN partials
__device__ __align__(16) float    g_consts[1536];              // scale,shift,d0,s0,s1,s2 per ch

__device__ __forceinline__ float bf2f(ushort_t u) {
    return __uint_as_float(((unsigned int)u) << 16);
}
__device__ __forceinline__ ushort_t f2bf(float f) {
    unsigned int x = __float_as_uint(f);
    return (ushort_t)((x + 0x7FFFu + ((x >> 16) & 1u)) >> 16);  // RNE
}
// Per-wave dtype probe: bf16 verts look plausible as bf16; f32 low halves don't.
__device__ __forceinline__ int probe_f32(const void* verts, int lane) {
    float ax = fabsf(bf2f(((const ushort_t*)verts)[lane]));
    unsigned long long b = __ballot((ax > 1e-5f) && (ax < 32.0f));
    return (__popcll(b) >= 56) ? 0 : 1;
}

// ---------------------------------------------------------------------------
// Kernel 1: atomic-free neighbor histogram partials + W -> bf16.
// Blocks [0,128): block b owns samples [b*4096,(b+1)*4096) -- all in batch
// b>>5 -- LDS-histograms them over the batch's 4096 vertices, stores partials.
// Blocks [128,160): convert W (32768 elems).
// ---------------------------------------------------------------------------
__global__ __launch_bounds__(256)
void hist_kernel(const int* __restrict__ nbr,
                 const void* __restrict__ Wg,
                 const void* __restrict__ verts) {
    __shared__ int h[4096];
    const int b   = blockIdx.x;
    const int tid = threadIdx.x;
    if (b < HB) {
        #pragma unroll
        for (int i = 0; i < 16; ++i) h[i * 256 + tid] = 0;
        __syncthreads();
        const int* src = nbr + (size_t)b * 4096;
        #pragma unroll
        for (int i = 0; i < 16; ++i) atomicAdd(&h[src[i * 256 + tid]], 1);  // LDS atomics only
        __syncthreads();
        int* dst = g_hp + (size_t)b * 4096;
        #pragma unroll
        for (int i = 0; i < 16; ++i) dst[i * 256 + tid] = h[i * 256 + tid];
    } else {
        const int f32 = probe_f32(verts, tid & 63);
        int i = (b - HB) * 1024 + tid * 4;
        if (f32) {
            float4 v = ((const float4*)Wg)[i >> 2];
            g_wb[i] = f2bf(v.x); g_wb[i + 1] = f2bf(v.y);
            g_wb[i + 2] = f2bf(v.z); g_wb[i + 3] = f2bf(v.w);
        } else {
            *(uint2*)(g_wb + i) = *(const uint2*)((const ushort_t*)Wg + i);
        }
    }
}

// ---------------------------------------------------------------------------
// Kernel 2: fused fsp-build + Y-GEMM + BN partial stats (no atomics).
// Stages 64 rows of [bf16(feat 0..126) ++ bf16(||row||)] straight from
// feature_map into LDS, then M=64 x N=256 x K=128 MFMA GEMM; epilogue stores
// Y bf16 + per-block mult-weighted sum/sumsq partials to g_sp[block].
// ---------------------------------------------------------------------------
__global__ __launch_bounds__(256, 2)
void ygemm_kernel(const void* __restrict__ fm, const void* __restrict__ verts) {
    __shared__ __align__(16) ushort_t At[64 * LDA];
    __shared__ float multS[64];

    const int tid  = threadIdx.x;
    const int r0   = blockIdx.x * 64;
    const int lane = tid & 63;
    const int f32  = probe_f32(verts, lane);

    if (tid < 64) {   // multiplicity = sum of the batch's 32 histogram partials
        const int* hp = g_hp + (size_t)(r0 >> 12) * 32 * 4096 + (r0 & 4095) + tid;
        int s = 0;
        #pragma unroll
        for (int p2 = 0; p2 < 32; ++p2) s += hp[(size_t)p2 * 4096];
        multS[tid] = (float)s;
    }

    const int rl4 = tid >> 6;
    #pragma unroll 4
    for (int i = 0; i < 16; ++i) {
        const int rl = i * 4 + rl4;
        float f0, f1; ushort_t u0, u1;
        if (f32) {
            const float* src = (const float*)fm + (size_t)(r0 + rl) * 127;
            f0 = src[lane];
            f1 = (lane < 63) ? src[64 + lane] : 0.0f;
            u0 = f2bf(f0); u1 = f2bf(f1);
        } else {
            const ushort_t* src = (const ushort_t*)fm + (size_t)(r0 + rl) * 127;
            u0 = src[lane];
            u1 = (lane < 63) ? src[64 + lane] : (ushort_t)0;
            f0 = bf2f(u0); f1 = bf2f(u1);
        }
        float ss = f0 * f0 + f1 * f1;                 // fdist in fp32 (matches ref)
        #pragma unroll
        for (int d = 1; d < 64; d <<= 1) ss += __shfl_xor(ss, d, 64);
        At[rl * LDA + lane]      = u0;
        At[rl * LDA + 64 + lane] = (lane < 63) ? u1 : f2bf(sqrtf(ss));
    }
    __syncthreads();

    const int w = tid >> 6;              // wave -> channel strip w*64
    const int m = lane & 15;
    const int q = lane >> 4;

    floatx4 acc[4][4];
    #pragma unroll
    for (int rt = 0; rt < 4; ++rt)
        #pragma unroll
        for (int ct = 0; ct < 4; ++ct)
            acc[rt][ct] = (floatx4){0.0f, 0.0f, 0.0f, 0.0f};

    #pragma unroll
    for (int kk = 0; kk < 4; ++kk) {
        const int kof = kk * 32 + q * 8;
        short8 af[4];
        #pragma unroll
        for (int rt = 0; rt < 4; ++rt)
            af[rt] = *(const short8*)&At[(rt * 16 + m) * LDA + kof];
        short8 bfr[4];
        #pragma unroll
        for (int ct = 0; ct < 4; ++ct) {
            int ch = w * 64 + ct * 16 + m;
            bfr[ct] = *(const short8*)(g_wb + ch * CIN + kof);  // B[k][n]=W[n][k]
        }
        #pragma unroll
        for (int rt = 0; rt < 4; ++rt)
            #pragma unroll
            for (int ct = 0; ct < 4; ++ct)
                acc[rt][ct] = __builtin_amdgcn_mfma_f32_16x16x32_bf16(
                    af[rt], bfr[ct], acc[rt][ct], 0, 0, 0);
    }

    #pragma unroll
    for (int ct = 0; ct < 4; ++ct) {
        const int ch = w * 64 + ct * 16 + m;
        float s = 0.0f, ss = 0.0f;
        #pragma unroll
        for (int rt = 0; rt < 4; ++rt)
            #pragma unroll
            for (int j = 0; j < 4; ++j) {
                int rloc = rt * 16 + q * 4 + j;       // C/D: row=(lane>>4)*4+reg
                ushort_t yb = f2bf(acc[rt][ct][j]);
                g_y[(size_t)(r0 + rloc) * COUT + ch] = yb;
                float yv = bf2f(yb);                  // same value epi will read
                float wm = multS[rloc];
                s  += wm * yv;
                ss += wm * yv * yv;
            }
        s  += __shfl_xor(s, 16, 64);  s  += __shfl_xor(s, 32, 64);
        ss += __shfl_xor(ss, 16, 64); ss += __shfl_xor(ss, 32, 64);
        if (q == 0) {                                 // plain stores, no atomics
            g_sp[(size_t)blockIdx.x * 512 + ch]       = s;
            g_sp[(size_t)blockIdx.x * 512 + 256 + ch] = ss;
        }
    }
}

// ---------------------------------------------------------------------------
// Kernel 3: reduce the 256 BN partials + per-channel constants.
// bias b cancels exactly in train-mode BN (z - mean(z)) -> never read.
// ---------------------------------------------------------------------------
__global__ void finalize_kernel(const void* __restrict__ gamma,
                                const void* __restrict__ beta,
                                const void* __restrict__ dirs,
                                const void* __restrict__ verts) {
    const int c   = threadIdx.x;                      // 256 threads, 1 block
    const int f32 = probe_f32(verts, c & 63);

    float s = 0.0f, ss = 0.0f;
    #pragma unroll 8
    for (int p2 = 0; p2 < 256; ++p2) {
        s  += g_sp[(size_t)p2 * 512 + c];
        ss += g_sp[(size_t)p2 * 512 + 256 + c];
    }
    const float invN = 1.0f / (float)NSAMP;
    float mean = s * invN;
    float var  = fmaxf(ss * invN - mean * mean, 0.0f);  // biased
    float inv  = 1.0f / sqrtf(var + 1e-5f);
    float ga, be, d0, d1, d2, d3;
    if (f32) {
        ga = ((const float*)gamma)[c]; be = ((const float*)beta)[c];
        const float* dd = (const float*)dirs;
        d0 = dd[c]; d1 = dd[256 + c]; d2 = dd[512 + c]; d3 = dd[768 + c];
    } else {
        ga = bf2f(((const ushort_t*)gamma)[c]); be = bf2f(((const ushort_t*)beta)[c]);
        const ushort_t* dd = (const ushort_t*)dirs;
        d0 = bf2f(dd[c]); d1 = bf2f(dd[256 + c]);
        d2 = bf2f(dd[512 + c]); d3 = bf2f(dd[768 + c]);
    }
    float scale = ga * inv;
    g_consts[c]        = scale;
    g_consts[256 + c]  = be - mean * scale;
    g_consts[512 + c]  = d0;                          // directions[0]
    g_consts[768 + c]  = d1 - d0;                     // sup_w rows
    g_consts[1024 + c] = d2 - d0;
    g_consts[1280 + c] = d3 - d0;
}

// ---------------------------------------------------------------------------
// Kernel 4: epilogue, one WAVE per point, 4 channels per lane (low VGPR:
// 6 floatx4 consts=24 + acc 8 + 4-deep pipeline 24 ~= 80 peak, far under the
// 128 cap of launch_bounds(256,4) -> no spill possible; the previous 8-ch
// variant sat at ~120-130 and likely spilled under the forced cap).
// 256 thr / 4 waves / 4 points per block -> 4096 blocks. Per neighbor: one
// broadcast ds_read_b128 (row packed in dws[].w) + one dwordx2 gather; a
// wave's 64 lanes x 8B cover the point's full 512B g_y row per instruction.
// One barrier, no cross-wave combine. XCD-chunked: blocks with bid&7==k
// cover p in [k*2048,(k+1)*2048) -> per-XCD gather set = one batch's 2MB
// g_y slice (< 4MB per-XCD L2).
// ---------------------------------------------------------------------------
__global__ __launch_bounds__(256, 4)
void epi_kernel(const int* __restrict__ nbr,
                const void* __restrict__ verts,
                void* __restrict__ out) {
    __shared__ float4 dws[4][NN];                     // {wx,wy,wz, asfloat(row)}

    const int tid  = threadIdx.x;
    const int lane = tid & 63;
    const int bid  = blockIdx.x;
    const int p0   = (((bid & 7) << 9) | (bid >> 3)) << 2;   // XCD-chunked, 4 pts
    const int f32  = probe_f32(verts, lane);

    if (tid < 128) {   // setup: 4 points x 32 neighbors, one pair per thread
        const int pt = tid >> 5, j = tid & 31;
        const int p  = p0 + pt;
        int gv = ((p >> 12) << 12) + nbr[(size_t)p * NN + j];
        float sx, sy, sz, nx, ny, nz;
        if (f32) {
            const float* vv = (const float*)verts;
            sx = vv[p * 3]; sy = vv[p * 3 + 1]; sz = vv[p * 3 + 2];
            nx = vv[gv * 3]; ny = vv[gv * 3 + 1]; nz = vv[gv * 3 + 2];
        } else {
            const ushort_t* vv = (const ushort_t*)verts;
            sx = bf2f(vv[p * 3]); sy = bf2f(vv[p * 3 + 1]); sz = bf2f(vv[p * 3 + 2]);
            nx = bf2f(vv[gv * 3]); ny = bf2f(vv[gv * 3 + 1]); nz = bf2f(vv[gv * 3 + 2]);
        }
        float dx = nx - sx, dy = ny - sy, dz = nz - sz;
        float nrm = sqrtf(dx * dx + dy * dy + dz * dz);
        float inv = 1.0f / fmaxf(nrm, 1e-12f);            // F.normalize eps
        dws[pt][j] = make_float4((dx * inv + 1.0f) * 0.5f,
                                 (dy * inv + 1.0f) * 0.5f,
                                 (dz * inv + 1.0f) * 0.5f,
                                 __int_as_float(gv));
    }
    __syncthreads();                                  // the only barrier

    const int w  = tid >> 6;                          // wave -> point
    const int p  = p0 + w;
    const int c4 = lane * 4;                          // 4 channels per lane
    const floatx4 zero = {0.0f, 0.0f, 0.0f, 0.0f};
    const floatx4 sc = *(const floatx4*)&g_consts[c4];
    const floatx4 sh = *(const floatx4*)&g_consts[256 + c4];
    const floatx4 d0 = *(const floatx4*)&g_consts[512 + c4];
    const floatx4 s0 = *(const floatx4*)&g_consts[768 + c4];
    const floatx4 s1 = *(const floatx4*)&g_consts[1024 + c4];
    const floatx4 s2 = *(const floatx4*)&g_consts[1280 + c4];

    const float4* dwp = dws[w];
    floatx4 vmA = zero, vmB = zero;                   // 2 chains break serial max

    for (int j0 = 0; j0 < NN; j0 += 4) {
        float4 dw[4]; uint2 u[4];
        #pragma unroll
        for (int jj = 0; jj < 4; ++jj) {              // 4 gathers in flight
            dw[jj] = dwp[j0 + jj];                    // ds_read_b128 (bcast)
            int row = __float_as_int(dw[jj].w);
            u[jj] = *(const uint2*)(g_y + ((size_t)row << 8) + c4);
        }
        #pragma unroll
        for (int jj = 0; jj < 4; ++jj) {
            floatx4 y;
            y.x = __uint_as_float(u[jj].x << 16);
            y.y = __uint_as_float(u[jj].x & 0xFFFF0000u);
            y.z = __uint_as_float(u[jj].y << 16);
            y.w = __uint_as_float(u[jj].y & 0xFFFF0000u);
            floatx4 th = d0 + s0 * dw[jj].x + s1 * dw[jj].y + s2 * dw[jj].z;
            th = __builtin_elementwise_max(th, zero);
            floatx4 zt = (y * sc + sh) * th;          // relu(z)*th == max(z*th,0)
            if (jj & 1) vmB = __builtin_elementwise_max(vmB, zt);
            else        vmA = __builtin_elementwise_max(vmA, zt);
        }
    }
    floatx4 vm = __builtin_elementwise_max(vmA, vmB); // accs >= 0 -> clamp built in

    size_t ofs = (size_t)p * COUT + c4;
    if (f32) {
        *(floatx4*)((float*)out + ofs) = vm;
    } else {
        uint2 ou;
        ou.x = ((unsigned int)f2bf(vm.y) << 16) | (unsigned int)f2bf(vm.x);
        ou.y = ((unsigned int)f2bf(vm.w) << 16) | (unsigned int)f2bf(vm.z);
        *(uint2*)((ushort_t*)out + ofs) = ou;
    }
}

// ---------------------------------------------------------------------------
extern "C" void kernel_launch(void* const* d_in, const int* in_sizes, int n_in,
                              void* d_out, int out_size, void* d_ws, size_t ws_size,
                              hipStream_t stream) {
    const int* nbr    = (const int*)d_in[0];
    const void* verts = d_in[1];
    const void* fm    = d_in[2];
    const void* dirs  = d_in[3];
    const void* Wg    = d_in[4];
    // d_in[5] = b: cancels exactly under train-mode BatchNorm -> unused
    const void* gamma = d_in[6];
    const void* beta  = d_in[7];
    (void)d_ws; (void)ws_size; (void)in_sizes; (void)n_in; (void)out_size;

    hist_kernel<<<dim3(HB + 32), dim3(256), 0, stream>>>(nbr, Wg, verts);
    ygemm_kernel<<<dim3(NPTS / 64), dim3(256), 0, stream>>>(fm, verts);
    finalize_kernel<<<dim3(1), dim3(256), 0, stream>>>(gamma, beta, dirs, verts);
    epi_kernel<<<dim3(NPTS / 4), dim3(256), 0, stream>>>(nbr, verts, d_out);
}

// Round 5
// 140.505 us; speedup vs baseline: 1.0034x; 1.0034x over previous
//
#include <hip/hip_runtime.h>

typedef unsigned short ushort_t;
typedef __attribute__((ext_vector_type(8))) short short8;   // 8 bf16 payload (4 VGPRs)
typedef __attribute__((ext_vector_type(4))) float floatx4;  // MFMA C/D + epi math
typedef __attribute__((ext_vector_type(2))) float floatx2;

#define NN    32
#define CIN   128
#define COUT  256
#define NPTS  16384            // bs*v = 4*4096
#define NSAMP (NPTS * NN)      // 524288
#define LDA   136              // LDS A-tile stride (+16B pad)
#define HB    128              // histogram partial blocks (32 per batch)

// All scratch in .so-resident device globals. NO atomics anywhere -> every
// buffer is fully overwritten each run -> no zeroing kernel, no cross-run state.
__device__ __align__(16) ushort_t g_wb[COUT * CIN];            // 64 KB: W as bf16
__device__ __align__(16) ushort_t g_y[(size_t)NPTS * COUT];    // 8 MB: Y = fsp * W^T, bf16
__device__ __align__(16) int      g_hp[HB * 4096];             // 2 MB: per-chunk histograms
__device__ __align__(16) float    g_sp[256 * 512];             // 512 KB: per-block BN partials
__device__ __align__(16) float    g_consts[1536];              // scale,shift,d0,s0,s1,s2 per ch

__device__ __forceinline__ float bf2f(ushort_t u) {
    return __uint_as_float(((unsigned int)u) << 16);
}
__device__ __forceinline__ ushort_t f2bf(float f) {
    unsigned int x = __float_as_uint(f);
    return (ushort_t)((x + 0x7FFFu + ((x >> 16) & 1u)) >> 16);  // RNE
}
// Per-wave dtype probe: bf16 verts look plausible as bf16; f32 low halves don't.
__device__ __forceinline__ int probe_f32(const void* verts, int lane) {
    float ax = fabsf(bf2f(((const ushort_t*)verts)[lane]));
    unsigned long long b = __ballot((ax > 1e-5f) && (ax < 32.0f));
    return (__popcll(b) >= 56) ? 0 : 1;
}
__device__ __forceinline__ float lanebcast(float v, int jj) {
    return __uint_as_float((unsigned)__builtin_amdgcn_readlane(__float_as_int(v), jj));
}

// ---------------------------------------------------------------------------
// Kernel 1: atomic-free neighbor histogram partials + W -> bf16.
// Blocks [0,128): block b owns samples [b*4096,(b+1)*4096) -- all in batch
// b>>5 -- LDS-histograms them over the batch's 4096 vertices, stores partials.
// Blocks [128,160): convert W (32768 elems).
// ---------------------------------------------------------------------------
__global__ __launch_bounds__(256)
void hist_kernel(const int* __restrict__ nbr,
                 const void* __restrict__ Wg,
                 const void* __restrict__ verts) {
    __shared__ int h[4096];
    const int b   = blockIdx.x;
    const int tid = threadIdx.x;
    if (b < HB) {
        #pragma unroll
        for (int i = 0; i < 16; ++i) h[i * 256 + tid] = 0;
        __syncthreads();
        const int* src = nbr + (size_t)b * 4096;
        #pragma unroll
        for (int i = 0; i < 16; ++i) atomicAdd(&h[src[i * 256 + tid]], 1);  // LDS atomics only
        __syncthreads();
        int* dst = g_hp + (size_t)b * 4096;
        #pragma unroll
        for (int i = 0; i < 16; ++i) dst[i * 256 + tid] = h[i * 256 + tid];
    } else {
        const int f32 = probe_f32(verts, tid & 63);
        int i = (b - HB) * 1024 + tid * 4;
        if (f32) {
            float4 v = ((const float4*)Wg)[i >> 2];
            g_wb[i] = f2bf(v.x); g_wb[i + 1] = f2bf(v.y);
            g_wb[i + 2] = f2bf(v.z); g_wb[i + 3] = f2bf(v.w);
        } else {
            *(uint2*)(g_wb + i) = *(const uint2*)((const ushort_t*)Wg + i);
        }
    }
}

// ---------------------------------------------------------------------------
// Kernel 2: fused fsp-build + Y-GEMM + BN partial stats (no atomics).
// Stages 64 rows of [bf16(feat 0..126) ++ bf16(||row||)] straight from
// feature_map into LDS, then M=64 x N=256 x K=128 MFMA GEMM; epilogue stores
// Y bf16 + per-block mult-weighted sum/sumsq partials to g_sp[block].
// ---------------------------------------------------------------------------
__global__ __launch_bounds__(256, 2)
void ygemm_kernel(const void* __restrict__ fm, const void* __restrict__ verts) {
    __shared__ __align__(16) ushort_t At[64 * LDA];
    __shared__ float multS[64];

    const int tid  = threadIdx.x;
    const int r0   = blockIdx.x * 64;
    const int lane = tid & 63;
    const int f32  = probe_f32(verts, lane);

    if (tid < 64) {   // multiplicity = sum of the batch's 32 histogram partials
        const int* hp = g_hp + (size_t)(r0 >> 12) * 32 * 4096 + (r0 & 4095) + tid;
        int s = 0;
        #pragma unroll
        for (int p2 = 0; p2 < 32; ++p2) s += hp[(size_t)p2 * 4096];
        multS[tid] = (float)s;
    }

    const int rl4 = tid >> 6;
    #pragma unroll 4
    for (int i = 0; i < 16; ++i) {
        const int rl = i * 4 + rl4;
        float f0, f1; ushort_t u0, u1;
        if (f32) {
            const float* src = (const float*)fm + (size_t)(r0 + rl) * 127;
            f0 = src[lane];
            f1 = (lane < 63) ? src[64 + lane] : 0.0f;
            u0 = f2bf(f0); u1 = f2bf(f1);
        } else {
            const ushort_t* src = (const ushort_t*)fm + (size_t)(r0 + rl) * 127;
            u0 = src[lane];
            u1 = (lane < 63) ? src[64 + lane] : (ushort_t)0;
            f0 = bf2f(u0); f1 = bf2f(u1);
        }
        float ss = f0 * f0 + f1 * f1;                 // fdist in fp32 (matches ref)
        #pragma unroll
        for (int d = 1; d < 64; d <<= 1) ss += __shfl_xor(ss, d, 64);
        At[rl * LDA + lane]      = u0;
        At[rl * LDA + 64 + lane] = (lane < 63) ? u1 : f2bf(sqrtf(ss));
    }
    __syncthreads();

    const int w = tid >> 6;              // wave -> channel strip w*64
    const int m = lane & 15;
    const int q = lane >> 4;

    floatx4 acc[4][4];
    #pragma unroll
    for (int rt = 0; rt < 4; ++rt)
        #pragma unroll
        for (int ct = 0; ct < 4; ++ct)
            acc[rt][ct] = (floatx4){0.0f, 0.0f, 0.0f, 0.0f};

    #pragma unroll
    for (int kk = 0; kk < 4; ++kk) {
        const int kof = kk * 32 + q * 8;
        short8 af[4];
        #pragma unroll
        for (int rt = 0; rt < 4; ++rt)
            af[rt] = *(const short8*)&At[(rt * 16 + m) * LDA + kof];
        short8 bfr[4];
        #pragma unroll
        for (int ct = 0; ct < 4; ++ct) {
            int ch = w * 64 + ct * 16 + m;
            bfr[ct] = *(const short8*)(g_wb + ch * CIN + kof);  // B[k][n]=W[n][k]
        }
        #pragma unroll
        for (int rt = 0; rt < 4; ++rt)
            #pragma unroll
            for (int ct = 0; ct < 4; ++ct)
                acc[rt][ct] = __builtin_amdgcn_mfma_f32_16x16x32_bf16(
                    af[rt], bfr[ct], acc[rt][ct], 0, 0, 0);
    }

    #pragma unroll
    for (int ct = 0; ct < 4; ++ct) {
        const int ch = w * 64 + ct * 16 + m;
        float s = 0.0f, ss = 0.0f;
        #pragma unroll
        for (int rt = 0; rt < 4; ++rt)
            #pragma unroll
            for (int j = 0; j < 4; ++j) {
                int rloc = rt * 16 + q * 4 + j;       // C/D: row=(lane>>4)*4+reg
                ushort_t yb = f2bf(acc[rt][ct][j]);
                g_y[(size_t)(r0 + rloc) * COUT + ch] = yb;
                float yv = bf2f(yb);                  // same value epi will read
                float wm = multS[rloc];
                s  += wm * yv;
                ss += wm * yv * yv;
            }
        s  += __shfl_xor(s, 16, 64);  s  += __shfl_xor(s, 32, 64);
        ss += __shfl_xor(ss, 16, 64); ss += __shfl_xor(ss, 32, 64);
        if (q == 0) {                                 // plain stores, no atomics
            g_sp[(size_t)blockIdx.x * 512 + ch]       = s;
            g_sp[(size_t)blockIdx.x * 512 + 256 + ch] = ss;
        }
    }
}

// ---------------------------------------------------------------------------
// Kernel 3: reduce the 256 BN partials + per-channel constants.
// bias b cancels exactly in train-mode BN (z - mean(z)) -> never read.
// ---------------------------------------------------------------------------
__global__ void finalize_kernel(const void* __restrict__ gamma,
                                const void* __restrict__ beta,
                                const void* __restrict__ dirs,
                                const void* __restrict__ verts) {
    const int c   = threadIdx.x;                      // 256 threads, 1 block
    const int f32 = probe_f32(verts, c & 63);

    float s = 0.0f, ss = 0.0f;
    #pragma unroll 8
    for (int p2 = 0; p2 < 256; ++p2) {
        s  += g_sp[(size_t)p2 * 512 + c];
        ss += g_sp[(size_t)p2 * 512 + 256 + c];
    }
    const float invN = 1.0f / (float)NSAMP;
    float mean = s * invN;
    float var  = fmaxf(ss * invN - mean * mean, 0.0f);  // biased
    float inv  = 1.0f / sqrtf(var + 1e-5f);
    float ga, be, d0, d1, d2, d3;
    if (f32) {
        ga = ((const float*)gamma)[c]; be = ((const float*)beta)[c];
        const float* dd = (const float*)dirs;
        d0 = dd[c]; d1 = dd[256 + c]; d2 = dd[512 + c]; d3 = dd[768 + c];
    } else {
        ga = bf2f(((const ushort_t*)gamma)[c]); be = bf2f(((const ushort_t*)beta)[c]);
        const ushort_t* dd = (const ushort_t*)dirs;
        d0 = bf2f(dd[c]); d1 = bf2f(dd[256 + c]);
        d2 = bf2f(dd[512 + c]); d3 = bf2f(dd[768 + c]);
    }
    float scale = ga * inv;
    g_consts[c]        = scale;
    g_consts[256 + c]  = be - mean * scale;
    g_consts[512 + c]  = d0;                          // directions[0]
    g_consts[768 + c]  = d1 - d0;                     // sup_w rows
    g_consts[1024 + c] = d2 - d0;
    g_consts[1280 + c] = d3 - d0;
}

// ---------------------------------------------------------------------------
// Kernel 4: epilogue, barrier-free / LDS-free. One wave per point, 4 ch/lane.
// Lane j (and its j+32 twin) computes neighbor j's direction weights + row
// index and KEEPS THEM IN VGPRs; the main loop broadcasts them with
// v_readlane -> row lands in an SGPR, so each gather is
// global_load_dwordx2 v,voff,s[base] with ZERO per-lane address math (SALU
// builds the base, co-issued). No ds_read in the chain, no __syncthreads
// anywhere -> each wave starts gathering right after its own setup.
// 8-deep load pipeline (prologue 8, prefetch-8-ahead) doubles latency
// tolerance vs the previous 4-deep; launch_bounds(256,5) caps VGPR at ~102
// (est. ~90 live) for >=5 waves/SIMD. XCD-chunked: blocks with bid&7==k
// cover p in [k*2048,(k+1)*2048) -> per-XCD gather set = one batch's 2MB
// g_y slice (< 4MB per-XCD L2).
// ---------------------------------------------------------------------------
__global__ __launch_bounds__(256, 5)
void epi_kernel(const int* __restrict__ nbr,
                const void* __restrict__ verts,
                void* __restrict__ out) {
    const int tid  = threadIdx.x;
    const int lane = tid & 63;
    const int bid  = blockIdx.x;
    const int p0   = (((bid & 7) << 9) | (bid >> 3)) << 2;   // XCD-chunked, 4 pts
    const int p    = p0 + (tid >> 6);                        // wave -> point
    const int f32  = probe_f32(verts, lane);
    const int j    = lane & 31;                              // owned neighbor

    // --- setup: per-lane direction weight + row, held in VGPRs (no LDS) ---
    int   gv;                                                // gathered row
    float wx, wy, wz;
    {
        gv = ((p >> 12) << 12) + nbr[(size_t)p * NN + j];
        float sx, sy, sz, nx, ny, nz;
        if (f32) {
            const float* vv = (const float*)verts;
            sx = vv[p * 3]; sy = vv[p * 3 + 1]; sz = vv[p * 3 + 2];
            nx = vv[gv * 3]; ny = vv[gv * 3 + 1]; nz = vv[gv * 3 + 2];
        } else {
            const ushort_t* vv = (const ushort_t*)verts;
            sx = bf2f(vv[p * 3]); sy = bf2f(vv[p * 3 + 1]); sz = bf2f(vv[p * 3 + 2]);
            nx = bf2f(vv[gv * 3]); ny = bf2f(vv[gv * 3 + 1]); nz = bf2f(vv[gv * 3 + 2]);
        }
        float dx = nx - sx, dy = ny - sy, dz = nz - sz;
        float nrm = sqrtf(dx * dx + dy * dy + dz * dz);
        float inv = 1.0f / fmaxf(nrm, 1e-12f);               // F.normalize eps
        wx = (dx * inv + 1.0f) * 0.5f;
        wy = (dy * inv + 1.0f) * 0.5f;
        wz = (dz * inv + 1.0f) * 0.5f;
    }

    const int c4 = lane * 4;                                 // 4 channels per lane
    const floatx4 zero = {0.0f, 0.0f, 0.0f, 0.0f};
    const floatx4 sc = *(const floatx4*)&g_consts[c4];
    const floatx4 sh = *(const floatx4*)&g_consts[256 + c4];
    const floatx4 d0 = *(const floatx4*)&g_consts[512 + c4];
    const floatx4 s0 = *(const floatx4*)&g_consts[768 + c4];
    const floatx4 s1 = *(const floatx4*)&g_consts[1024 + c4];
    const floatx4 s2 = *(const floatx4*)&g_consts[1280 + c4];

    floatx4 vmA = zero, vmB = zero;                          // 2 max chains
    uint2 u[8];                                              // 8-deep pipeline

    #pragma unroll
    for (int k = 0; k < 8; ++k) {                            // prologue: 8 loads
        int r = __builtin_amdgcn_readlane(gv, k);            // SGPR row
        u[k] = *(const uint2*)(g_y + ((size_t)(unsigned)r << 8) + c4);
    }
    #pragma unroll
    for (int g = 0; g < 4; ++g) {
        #pragma unroll
        for (int k = 0; k < 8; ++k) {
            const int jj = g * 8 + k;
            const uint2 uk = u[k];                           // waits this load only
            if (g < 3) {                                     // prefetch 8 ahead
                int r = __builtin_amdgcn_readlane(gv, jj + 8);
                u[k] = *(const uint2*)(g_y + ((size_t)(unsigned)r << 8) + c4);
            }
            float wxs = lanebcast(wx, jj);                   // uniform scalars
            float wys = lanebcast(wy, jj);
            float wzs = lanebcast(wz, jj);
            floatx4 y;
            y.x = __uint_as_float(uk.x << 16);
            y.y = __uint_as_float(uk.x & 0xFFFF0000u);
            y.z = __uint_as_float(uk.y << 16);
            y.w = __uint_as_float(uk.y & 0xFFFF0000u);
            floatx4 th = d0 + s0 * wxs + s1 * wys + s2 * wzs;
            th = __builtin_elementwise_max(th, zero);
            floatx4 zt = (y * sc + sh) * th;                 // relu(z)*th == max(z*th,0)
            if (k & 1) vmB = __builtin_elementwise_max(vmB, zt);
            else       vmA = __builtin_elementwise_max(vmA, zt);
        }
    }
    floatx4 vm = __builtin_elementwise_max(vmA, vmB);        // accs >= 0

    size_t ofs = (size_t)p * COUT + c4;
    if (f32) {
        *(floatx4*)((float*)out + ofs) = vm;
    } else {
        uint2 ou;
        ou.x = ((unsigned int)f2bf(vm.y) << 16) | (unsigned int)f2bf(vm.x);
        ou.y = ((unsigned int)f2bf(vm.w) << 16) | (unsigned int)f2bf(vm.z);
        *(uint2*)((ushort_t*)out + ofs) = ou;
    }
}

// ---------------------------------------------------------------------------
extern "C" void kernel_launch(void* const* d_in, const int* in_sizes, int n_in,
                              void* d_out, int out_size, void* d_ws, size_t ws_size,
                              hipStream_t stream) {
    const int* nbr    = (const int*)d_in[0];
    const void* verts = d_in[1];
    const void* fm    = d_in[2];
    const void* dirs  = d_in[3];
    const void* Wg    = d_in[4];
    // d_in[5] = b: cancels exactly under train-mode BatchNorm -> unused
    const void* gamma = d_in[6];
    const void* beta  = d_in[7];
    (void)d_ws; (void)ws_size; (void)in_sizes; (void)n_in; (void)out_size;

    hist_kernel<<<dim3(HB + 32), dim3(256), 0, stream>>>(nbr, Wg, verts);
    ygemm_kernel<<<dim3(NPTS / 64), dim3(256), 0, stream>>>(fm, verts);
    finalize_kernel<<<dim3(1), dim3(256), 0, stream>>>(gamma, beta, dirs, verts);
    epi_kernel<<<dim3(NPTS / 4), dim3(256), 0, stream>>>(nbr, verts, d_out);
}